// Round 5
// baseline (524.895 us; speedup 1.0000x reference)
//
#include <hip/hip_runtime.h>
#include <hip/hip_bf16.h>
#include <math.h>

#define BB  64
#define CC  512
#define NN  4
#define KK  1024
#define DD  128
#define HW  1024
#define PP  65536

// d_out layout (float32, concatenated in return order)
#define OFF_DIFF 33554432UL
#define OFF_ARG  33554433UL
#define OFF_PPL  33816577UL

// d_ws layout (bytes)
#define WS_HIST   0
#define WS_DSUM   16384
#define WS_WLCNT  16392
#define WS_ENORM  16416
#define WS_EBF    32800                         // 128 tiles * 16384 B = 2 MiB (pre-swizzled bf16 hi/lo, 32 codes each)
#define WS_EMBT   (32800 + 128*16384)           // fp32 embed_t[n][k][d], 2 MiB
#define WS_WL     (WS_EMBT + NN*KK*DD*4)

#define DELTA 0.0625f   // near-tie margin -> fp64 re-check

typedef short s16x8 __attribute__((ext_vector_type(8)));
typedef float f32x4 __attribute__((ext_vector_type(4)));

__device__ __forceinline__ unsigned short f2bf(float f) {
    unsigned u = __builtin_bit_cast(unsigned, f);
    u += 0x7fffu + ((u >> 16) & 1u);
    return (unsigned short)(u >> 16);
}
__device__ __forceinline__ float bf2f(unsigned short h) {
    unsigned u = ((unsigned)h) << 16;
    return __builtin_bit_cast(float, u);
}
// swizzled byte offset for [row][128 bf16] tiles: XOR 16B-slot with row&15
__device__ __forceinline__ int swz(int row, int dbyte) {
    return (row * 256 + dbyte) ^ ((row & 15) << 4);
}
__device__ __forceinline__ void gl2lds16(const void* g, void* l) {
    __builtin_amdgcn_global_load_lds(
        (const __attribute__((address_space(1))) unsigned int*)g,
        (__attribute__((address_space(3))) unsigned int*)l, 16, 0, 0);
}

// ---- prep: embed -> pre-swizzled bf16 hi/lo 32-code tiles + fp32 embed_t + enorm
// grid 64 = n(4) x kt64(16); also zeroes hist/dsum/wlcnt (replaces memset)
__global__ __launch_bounds__(256) void vq_prep(const float* __restrict__ embed,
                                               char* __restrict__ ebf,
                                               float* __restrict__ embt,
                                               float* __restrict__ enorm,
                                               unsigned* __restrict__ hist,
                                               double* __restrict__ dsum,
                                               unsigned* __restrict__ wlcnt) {
    __shared__ float sred[4][64];
    const int e = blockIdx.x, n = e >> 4, kt = e & 15, k0 = kt * 64;
    const int t = threadIdx.x, kr = t & 63, dc = t >> 6;   // 4 d-chunks of 32
    // ws zeroing (64 blocks x 64 entries = 4096)
    if (t < 64) hist[e * 64 + t] = 0u;
    if (e == 0 && t == 0) { *dsum = 0.0; *wlcnt = 0u; }

    const float* src = embed + ((size_t)n * DD + dc * 32) * KK + k0 + kr;
    char* tile = ebf + ((size_t)n * 32 + kt * 2 + (kr >> 5)) * 16384;   // 32-code tile
    const int row = kr & 31;
    float fv[32];
    #pragma unroll
    for (int r = 0; r < 32; ++r) fv[r] = src[(size_t)r * KK];
    float s = 0.f;
    #pragma unroll
    for (int j = 0; j < 4; ++j) {
        s16x8 vh, vl;
        #pragma unroll
        for (int r = 0; r < 8; ++r) {
            float f = fv[j * 8 + r];
            unsigned short h = f2bf(f);
            vh[r] = (short)h;
            vl[r] = (short)f2bf(f - bf2f(h));
            s = fmaf(f, f, s);
        }
        int o = swz(row, (dc * 32 + j * 8) * 2);
        *(s16x8*)(tile + o)        = vh;
        *(s16x8*)(tile + 8192 + o) = vl;
    }
    // fp32 transposed codebook row: embt[(n*KK + k)][d]
    {
        float* drow = embt + ((size_t)n * KK + k0 + kr) * DD + dc * 32;
        #pragma unroll
        for (int j = 0; j < 8; ++j)
            *(float4*)(drow + j * 4) = make_float4(fv[j*4], fv[j*4+1], fv[j*4+2], fv[j*4+3]);
    }
    sred[dc][kr] = s;
    __syncthreads();
    if (t < 64) enorm[n * KK + k0 + t] = (sred[0][t] + sred[1][t]) + (sred[2][t] + sred[3][t]);
}

// ---- main ------------------------------------------------------------------
// 64 positions/block, 256 threads = 4 waves: 2 p-halves(32) x 2 k-halves(16 of 32-tile).
// LDS ~67KB -> 2 independent blocks/CU (decoupled barriers feed the MFMA pipe).
__global__ __launch_bounds__(256, 2) void vq_main(const float* __restrict__ x,
                                                  const char* __restrict__ ebf,
                                                  const float* __restrict__ embt,
                                                  const float* __restrict__ enormg,
                                                  float* __restrict__ out,
                                                  unsigned* __restrict__ hist,
                                                  double* __restrict__ dsum,
                                                  unsigned* __restrict__ wlcnt,
                                                  int2* __restrict__ wl, int wlcap) {
    __shared__ __attribute__((aligned(16))) unsigned short zs_hi[64 * 128];   // 16KB
    __shared__ __attribute__((aligned(16))) unsigned short zs_lo[64 * 128];   // 16KB
    __shared__ __attribute__((aligned(16))) unsigned short ebuf[2][8192];     // 2 x 16KB
    __shared__ int   idx_s[NN][64];
    __shared__ float red_b1[2][64], red_b2[2][64];
    __shared__ int   red_k1[2][64];
    __shared__ float wsum[4];

    const int t   = threadIdx.x;
    const int blk = blockIdx.x;                 // 1024 blocks: 16 per batch
    const int b   = blk >> 4;
    const int hw0 = (blk & 15) << 6;            // 64 consecutive positions
    const int w  = t >> 6, l = t & 63;
    const int pq = w >> 1;                      // p-half (32 rows)
    const int ks = w & 1;                       // k-half (16 of 32 per tile)
    const int tk = l & 15, lg = l >> 4;

    char* ebase = (char*)&ebuf[0][0];
    auto STAGE = [&](int bs, int nn, int kk) {  // kk in [0,32)
        const char* src = ebf + ((size_t)(nn * 32 + kk)) * 16384 + t * 16;
        char* dst = ebase + bs * 16384 + t * 16;
        #pragma unroll
        for (int j = 0; j < 4; ++j) gl2lds16(src + j * 4096, dst + j * 4096);
    };

    int bsel = 0;
    float znacc = 0.f, sumb1 = 0.f;

    for (int n = 0; n < NN; ++n) {
        __syncthreads();                        // zs / red / idx reuse guard
        if (n == 0) STAGE(0, 0, 0);             // overlap with z staging
        // ---- stage z (fp32 -> bf16 hi/lo, swizzled): row p, thread owns 32 d
        {
            const int p = t & 63, dchunk = t >> 6;
            const float* xp = x + ((size_t)b * CC + n * DD + dchunk * 32) * HW + hw0 + p;
            float fv[32];
            #pragma unroll
            for (int r = 0; r < 32; ++r) fv[r] = xp[(size_t)r * HW];
            #pragma unroll
            for (int j = 0; j < 4; ++j) {
                s16x8 vh, vl;
                #pragma unroll
                for (int r = 0; r < 8; ++r) {
                    float f = fv[j * 8 + r];
                    unsigned short hh = f2bf(f);
                    vh[r] = (short)hh;
                    vl[r] = (short)f2bf(f - bf2f(hh));
                    znacc = fmaf(f, f, znacc);
                }
                int o = swz(p, (dchunk * 32 + j * 8) * 2);
                *(s16x8*)((char*)zs_hi + o) = vh;
                *(s16x8*)((char*)zs_lo + o) = vl;
            }
        }
        __syncthreads();                        // zs + ebuf ready (vmcnt drained)

        // ---- A-fragments in registers for the whole n (16 frags = 64 VGPR)
        s16x8 a_hi[2][4], a_lo[2][4];
        #pragma unroll
        for (int mf = 0; mf < 2; ++mf)
            #pragma unroll
            for (int ds = 0; ds < 4; ++ds) {
                int o = swz(pq * 32 + mf * 16 + tk, (ds * 32 + lg * 8) * 2);
                a_hi[mf][ds] = *(const s16x8*)((const char*)zs_hi + o);
                a_lo[mf][ds] = *(const s16x8*)((const char*)zs_lo + o);
            }

        float b1v[8], b2v[8]; int k1v[8];       // r = mf*4+i -> p = pq*32+mf*16+lg*4+i
        #pragma unroll
        for (int r = 0; r < 8; ++r) { b1v[r] = INFINITY; b2v[r] = INFINITY; k1v[r] = 0; }

        for (int kt = 0; kt < 32; ++kt) {       // 32-code tiles
            if (kt < 31)      STAGE(bsel ^ 1, n, kt + 1);
            else if (n < 3)   STAGE(bsel ^ 1, n + 1, 0);

            const int kcol = kt * 32 + ks * 16 + tk;   // lane's single C column
            const float e2 = enormg[n * KK + kcol];

            f32x4 acc[2] = {f32x4{0,0,0,0}, f32x4{0,0,0,0}};
            #pragma unroll
            for (int ds = 0; ds < 4; ++ds) {
                int o = swz(ks * 16 + tk, (ds * 32 + lg * 8) * 2);
                s16x8 bh = *(const s16x8*)(ebase + bsel * 16384 + o);
                s16x8 bl = *(const s16x8*)(ebase + bsel * 16384 + 8192 + o);
                #pragma unroll
                for (int mf = 0; mf < 2; ++mf) {
                    acc[mf] = __builtin_amdgcn_mfma_f32_16x16x32_bf16(a_hi[mf][ds], bh, acc[mf], 0, 0, 0);
                    acc[mf] = __builtin_amdgcn_mfma_f32_16x16x32_bf16(a_lo[mf][ds], bh, acc[mf], 0, 0, 0);
                    acc[mf] = __builtin_amdgcn_mfma_f32_16x16x32_bf16(a_hi[mf][ds], bl, acc[mf], 0, 0, 0);
                }
            }
            // top-2: one k per lane per kt, kt ascending => first-min rule
            #pragma unroll
            for (int mf = 0; mf < 2; ++mf)
                #pragma unroll
                for (int i = 0; i < 4; ++i) {
                    float dv = fmaf(-2.f, acc[mf][i], e2);
                    int r = mf * 4 + i;
                    if (dv < b1v[r]) { b2v[r] = b1v[r]; b1v[r] = dv; k1v[r] = kcol; }
                    else             { b2v[r] = fminf(b2v[r], dv); }
                }
            __syncthreads();                    // buf swap guard
            bsel ^= 1;
        }

        // ---- merge across the 16 lane-columns (tk) of the wave
        #pragma unroll
        for (int off = 1; off < 16; off <<= 1) {
            #pragma unroll
            for (int r = 0; r < 8; ++r) {
                float ob1 = __shfl_xor(b1v[r], off);
                float ob2 = __shfl_xor(b2v[r], off);
                int   ok1 = __shfl_xor(k1v[r], off);
                float nb2 = fminf(b2v[r], ob2);
                if (ob1 < b1v[r] || (ob1 == b1v[r] && ok1 < k1v[r])) {
                    b2v[r] = fminf(nb2, b1v[r]); b1v[r] = ob1; k1v[r] = ok1;
                } else {
                    b2v[r] = fminf(nb2, ob1);
                }
            }
        }
        if (tk == 0) {
            #pragma unroll
            for (int mf = 0; mf < 2; ++mf)
                #pragma unroll
                for (int i = 0; i < 4; ++i) {
                    int p = pq * 32 + mf * 16 + lg * 4 + i, r = mf * 4 + i;
                    red_b1[ks][p] = b1v[r]; red_b2[ks][p] = b2v[r]; red_k1[ks][p] = k1v[r];
                }
        }
        __syncthreads();
        if (t < 64) {                           // merge the 2 k-halves
            int p = t;
            float m1 = red_b1[0][p], m2 = red_b2[0][p]; int mk = red_k1[0][p];
            {
                float ob1 = red_b1[1][p], ob2 = red_b2[1][p]; int ok = red_k1[1][p];
                float nb2 = fminf(m2, ob2);
                if (ob1 < m1 || (ob1 == m1 && ok < mk)) { m2 = fminf(nb2, m1); m1 = ob1; mk = ok; }
                else                                    { m2 = fminf(nb2, ob1); }
            }
            idx_s[n][p] = mk;
            atomicAdd(&hist[n * KK + mk], 1u);
            sumb1 += m1;                        // diff: ||z-q||^2 = znorm + (enorm - 2 z.e)
            if (m2 - m1 < DELTA) {
                unsigned pos = atomicAdd(wlcnt, 1u);
                if ((int)pos < wlcap) wl[pos] = make_int2(b * HW + hw0 + p, n);
            }
        }
    }

    // ---- diff partial reduce
    {
        float tot = znacc + sumb1;
        #pragma unroll
        for (int off = 32; off > 0; off >>= 1) tot += __shfl_down(tot, off);
        if (l == 0) wsum[w] = tot;
        __syncthreads();                        // also guards idx_s for epilogue
        if (t == 0) {
            double sd = 0.0;
            #pragma unroll
            for (int ww = 0; ww < 4; ++ww) sd += (double)wsum[ww];
            atomicAdd(dsum, sd);
        }
    }

    // ---- argmin output (as float): 4n x 64p = 256 = one per thread
    {
        int n2 = t >> 6, p = t & 63;
        out[OFF_ARG + (size_t)b * (NN * HW) + (size_t)n2 * HW + hw0 + p] = (float)idx_s[n2][p];
    }

    // ---- z_q gather: contiguous embed_t rows (L2-resident) + coalesced stores
    {
        const int p = t & 63, dchunk = t >> 6;
        #pragma unroll
        for (int n2 = 0; n2 < NN; ++n2) {
            int k = idx_s[n2][p];
            const float4* src = (const float4*)(embt + ((size_t)n2 * KK + k) * DD + dchunk * 32);
            const int c0 = n2 * 128 + dchunk * 32;
            #pragma unroll
            for (int r = 0; r < 8; ++r) {
                float4 q = src[r];
                out[((size_t)b * CC + c0 + r * 4 + 0) * HW + hw0 + p] = q.x;
                out[((size_t)b * CC + c0 + r * 4 + 1) * HW + hw0 + p] = q.y;
                out[((size_t)b * CC + c0 + r * 4 + 2) * HW + hw0 + p] = q.z;
                out[((size_t)b * CC + c0 + r * 4 + 3) * HW + hw0 + p] = q.w;
            }
        }
    }
}

// ---- fp64 exact re-check of near-ties (also fixes hist) --------------------
__global__ __launch_bounds__(256) void vq_refine(const float* __restrict__ x,
                                                 const float* __restrict__ embt,
                                                 float* __restrict__ out,
                                                 unsigned* __restrict__ hist,
                                                 const unsigned* __restrict__ wlcnt,
                                                 const int2* __restrict__ wl, int wlcap) {
    __shared__ double zd[DD];
    __shared__ double sval[256];
    __shared__ int    sidx[256];
    const int t = threadIdx.x;
    unsigned wc = *wlcnt;
    int nitems = (int)(wc < (unsigned)wlcap ? wc : (unsigned)wlcap);

    for (int it = blockIdx.x; it < nitems; it += gridDim.x) {
        int2 item = wl[it];
        int p = item.x, n = item.y;
        int b = p >> 10, hw = p & 1023;
        __syncthreads();
        if (t < DD) zd[t] = (double)x[((size_t)b * CC + n * DD + t) * HW + hw];
        __syncthreads();

        double lb = INFINITY; int lk = 0;
        for (int j = 0; j < 4; ++j) {
            int k = t * 4 + j;
            const float4* er = (const float4*)(embt + ((size_t)n * KK + k) * DD);
            double ss = 0.0, e2 = 0.0;
            #pragma unroll 8
            for (int r = 0; r < 32; ++r) {
                float4 v = er[r];
                double e0 = (double)v.x, e1 = (double)v.y, e2d = (double)v.z, e3 = (double)v.w;
                ss = fma(zd[r*4+0], e0, ss); e2 = fma(e0, e0, e2);
                ss = fma(zd[r*4+1], e1, ss); e2 = fma(e1, e1, e2);
                ss = fma(zd[r*4+2], e2d, ss); e2 = fma(e2d, e2d, e2);
                ss = fma(zd[r*4+3], e3, ss); e2 = fma(e3, e3, e2);
            }
            double dist = e2 - 2.0 * ss;
            if (dist < lb) { lb = dist; lk = k; }
        }
        sval[t] = lb; sidx[t] = lk;
        __syncthreads();
        for (int off = 128; off > 0; off >>= 1) {
            if (t < off) {
                double ov = sval[t + off]; int oi = sidx[t + off];
                if (ov < sval[t] || (ov == sval[t] && oi < sidx[t])) { sval[t] = ov; sidx[t] = oi; }
            }
            __syncthreads();
        }
        if (t == 0) {
            size_t slot = OFF_ARG + (size_t)b * (NN * HW) + (size_t)n * HW + hw;
            int oldk = (int)out[slot];
            int newk = sidx[0];
            if (newk != oldk) {
                out[slot] = (float)newk;
                atomicSub(&hist[n * KK + oldk], 1u);
                atomicAdd(&hist[n * KK + newk], 1u);
            }
        }
    }
}

__global__ __launch_bounds__(256) void vq_final(const unsigned* __restrict__ hist,
                                                const double* __restrict__ dsum,
                                                float* __restrict__ out) {
    __shared__ double red[256];
    __shared__ double hn[NN];
    const int t = threadIdx.x;
    for (int n = 0; n < NN; ++n) {
        double acc = 0.0;
        for (int k = t; k < KK; k += 256) {
            double pr = (double)hist[n * KK + k] / (double)PP;
            acc += pr * log(pr + 1e-10);
        }
        red[t] = acc;
        __syncthreads();
        for (int off = 128; off > 0; off >>= 1) {
            if (t < off) red[t] += red[t + off];
            __syncthreads();
        }
        if (t == 0) hn[n] = red[0];
        __syncthreads();
    }
    if (t == 0) {
        double ppl = 0.0;
        for (int n = 0; n < NN; ++n) ppl += exp(-hn[n]);
        out[OFF_PPL]  = (float)(ppl * 0.25);
        out[OFF_DIFF] = (float)(*dsum / (double)((size_t)BB * CC * HW));
    }
}

extern "C" void kernel_launch(void* const* d_in, const int* in_sizes, int n_in,
                              void* d_out, int out_size, void* d_ws, size_t ws_size,
                              hipStream_t stream) {
    const float* x     = (const float*)d_in[0];
    const float* embed = (const float*)d_in[1];
    float* out = (float*)d_out;
    char*  ws  = (char*)d_ws;

    unsigned* hist   = (unsigned*)(ws + WS_HIST);
    double*   dsum   = (double*)  (ws + WS_DSUM);
    unsigned* wlcnt  = (unsigned*)(ws + WS_WLCNT);
    float*    enorm  = (float*)   (ws + WS_ENORM);
    char*     ebf    = ws + WS_EBF;
    float*    embt   = (float*)   (ws + WS_EMBT);
    int2*     wl     = (int2*)    (ws + WS_WL);

    long long cap = ((long long)ws_size - WS_WL) / (long long)sizeof(int2);
    int wlcap = cap < 0 ? 0 : (cap > 65536 ? 65536 : (int)cap);

    vq_prep  <<<64,   256, 0, stream>>>(embed, ebf, embt, enorm, hist, dsum, wlcnt);
    vq_main  <<<1024, 256, 0, stream>>>(x, ebf, embt, enorm, out, hist, dsum, wlcnt, wl, wlcap);
    vq_refine<<<2048, 256, 0, stream>>>(x, embt, out, hist, wlcnt, wl, wlcap);
    vq_final <<<1,    256, 0, stream>>>(hist, dsum, out);
}

// Round 6
// 412.588 us; speedup vs baseline: 1.2722x; 1.2722x over previous
//
#include <hip/hip_runtime.h>
#include <math.h>

#define BB  64
#define CC  512
#define NN  4
#define KK  1024
#define DD  128
#define HW  1024
#define PP  65536

// d_out layout (float32, concatenated in return order)
#define OFF_DIFF 33554432UL
#define OFF_ARG  33554433UL
#define OFF_PPL  33816577UL

// d_ws layout (bytes)
#define WS_HIST   0
#define WS_DSUM   16384
#define WS_WLCNT  16392
#define WS_ENORM  16416
#define WS_EBF    32800                          // 128 tiles * 8192 B = 1 MiB (pre-swizzled fp16 eh, 32 codes x 128 d)
#define WS_EMBT   (32800 + 128*8192)             // fp32 embed_t[n][k][d], 2 MiB
#define WS_WL     (WS_EMBT + NN*KK*DD*4)

#define DELTA 0.0625f   // near-tie margin -> fp64 re-check

typedef _Float16 half8 __attribute__((ext_vector_type(8)));
typedef float f32x4 __attribute__((ext_vector_type(4)));

#define MFMA16(a, b, c) __builtin_amdgcn_mfma_f32_16x16x32_f16(a, b, c, 0, 0, 0)

// swizzled byte offset for [row][128 fp16] tiles (256B rows): XOR 16B-slot with row&15
__device__ __forceinline__ int swz(int row, int dbyte) {
    return (row * 256 + dbyte) ^ ((row & 15) << 4);
}
__device__ __forceinline__ void gl2lds16(const void* g, void* l) {
    __builtin_amdgcn_global_load_lds(
        (const __attribute__((address_space(1))) unsigned int*)g,
        (__attribute__((address_space(3))) unsigned int*)l, 16, 0, 0);
}

// ---- prep: embed -> pre-swizzled fp16 eh 32-code tiles + fp32 embed_t + enorm
// grid 64 = n(4) x kt64(16); also zeroes hist/dsum/wlcnt
__global__ __launch_bounds__(256) void vq_prep(const float* __restrict__ embed,
                                               char* __restrict__ ebf,
                                               float* __restrict__ embt,
                                               float* __restrict__ enorm,
                                               unsigned* __restrict__ hist,
                                               double* __restrict__ dsum,
                                               unsigned* __restrict__ wlcnt) {
    __shared__ float sred[4][64];
    const int e = blockIdx.x, n = e >> 4, kt = e & 15, k0 = kt * 64;
    const int t = threadIdx.x, kr = t & 63, dc = t >> 6;   // 4 d-chunks of 32
    if (t < 64) hist[e * 64 + t] = 0u;
    if (e == 0 && t == 0) { *dsum = 0.0; *wlcnt = 0u; }

    const float* src = embed + ((size_t)n * DD + dc * 32) * KK + k0 + kr;
    char* tile = ebf + ((size_t)(n * 32 + kt * 2 + (kr >> 5))) * 8192;
    const int row = kr & 31;
    float fv[32];
    #pragma unroll
    for (int r = 0; r < 32; ++r) fv[r] = src[(size_t)r * KK];
    float s = 0.f;
    #pragma unroll
    for (int j = 0; j < 4; ++j) {
        half8 vh;
        #pragma unroll
        for (int r = 0; r < 8; ++r) {
            float f = fv[j * 8 + r];
            vh[r] = (_Float16)f;
            s = fmaf(f, f, s);
        }
        *(half8*)(tile + swz(row, (dc * 32 + j * 8) * 2)) = vh;
    }
    {   // fp32 transposed codebook row for epilogue/refine
        float* drow = embt + ((size_t)n * KK + k0 + kr) * DD + dc * 32;
        #pragma unroll
        for (int j = 0; j < 8; ++j)
            *(float4*)(drow + j * 4) = make_float4(fv[j*4], fv[j*4+1], fv[j*4+2], fv[j*4+3]);
    }
    sred[dc][kr] = s;
    __syncthreads();
    if (t < 64) enorm[n * KK + k0 + t] = (sred[0][t] + sred[1][t]) + (sred[2][t] + sred[3][t]);
}

// top-2 update on one accumulator pair (mf half), unrolled => static indices
#define TOP2(C0, C1, MF, KP, E2)                                              \
    _Pragma("unroll")                                                         \
    for (int i_ = 0; i_ < 4; ++i_) {                                          \
        float dv_ = fmaf(-2.f, C0[i_] + C1[i_], E2);                          \
        int r_ = (MF) * 4 + i_;                                               \
        if (dv_ < b1v[r_]) { b2v[r_] = b1v[r_]; b1v[r_] = dv_; k1v[r_] = (KP); } \
        else b2v[r_] = fminf(b2v[r_], dv_);                                   \
    }

// one kt step: counted vmcnt + raw barrier; MFMA(kt)->AC while TOP2 consumes AP(kt-1)
#define STEP(J, AC, AP, E2C, E2P)                                             \
  {                                                                           \
    asm volatile("s_waitcnt vmcnt(2)" ::: "memory");                          \
    __builtin_amdgcn_s_barrier();                                             \
    __builtin_amdgcn_sched_barrier(0);                                        \
    const int kt_ = kt4 + (J);                                                \
    E2C = enls[(kt_ << 5) + koff];                                            \
    const char* bb_ = ebase + (J) * 8192;                                     \
    half8 bh0 = *(const half8*)(bb_ + bo0);                                   \
    half8 bh1 = *(const half8*)(bb_ + bo1);                                   \
    half8 bh2 = *(const half8*)(bb_ + bo2);                                   \
    half8 bh3 = *(const half8*)(bb_ + bo3);                                   \
    int g2_ = (n << 5) + kt_ + 2;                                             \
    if (g2_ < 128) {                                                          \
        const char* s_ = ebf + (size_t)g2_ * 8192 + t * 16;                   \
        char* d_ = ebase + (((J) + 2) & 3) * 8192 + t * 16;                   \
        gl2lds16(s_, d_);                                                     \
        gl2lds16(s_ + 4096, d_ + 4096);                                       \
    }                                                                         \
    AC##00 = zz4; AC##01 = zz4; AC##10 = zz4; AC##11 = zz4;                   \
    AC##00 = MFMA16(a_lo[0][0], bh0, AC##00);                                 \
    AC##00 = MFMA16(a_hi[0][0], bh0, AC##00);                                 \
    AC##00 = MFMA16(a_lo[0][1], bh1, AC##00);                                 \
    AC##00 = MFMA16(a_hi[0][1], bh1, AC##00);                                 \
    AC##01 = MFMA16(a_lo[0][2], bh2, AC##01);                                 \
    AC##01 = MFMA16(a_hi[0][2], bh2, AC##01);                                 \
    AC##01 = MFMA16(a_lo[0][3], bh3, AC##01);                                 \
    AC##01 = MFMA16(a_hi[0][3], bh3, AC##01);                                 \
    AC##10 = MFMA16(a_lo[1][0], bh0, AC##10);                                 \
    AC##10 = MFMA16(a_hi[1][0], bh0, AC##10);                                 \
    AC##10 = MFMA16(a_lo[1][1], bh1, AC##10);                                 \
    AC##10 = MFMA16(a_hi[1][1], bh1, AC##10);                                 \
    AC##11 = MFMA16(a_lo[1][2], bh2, AC##11);                                 \
    AC##11 = MFMA16(a_hi[1][2], bh2, AC##11);                                 \
    AC##11 = MFMA16(a_lo[1][3], bh3, AC##11);                                 \
    AC##11 = MFMA16(a_hi[1][3], bh3, AC##11);                                 \
    const int kp_ = ((kt_ - 1) << 5) + koff;                                  \
    TOP2(AP##00, AP##01, 0, kp_, E2P);                                        \
    TOP2(AP##10, AP##11, 1, kp_, E2P);                                        \
  }

// ---- main ------------------------------------------------------------------
// 64 positions/block, 256 threads = 4 waves: 2 p-halves(32) x 2 k-halves(16 of 32-tile)
// ~71KB LDS -> 2 blocks/CU; 1 raw barrier + counted vmcnt per kt; acc ping-pong.
__global__ __launch_bounds__(256, 2) void vq_main(const float* __restrict__ x,
                                                  const char* __restrict__ ebf,
                                                  const float* __restrict__ embt,
                                                  const float* __restrict__ enormg,
                                                  float* __restrict__ out,
                                                  unsigned* __restrict__ hist,
                                                  double* __restrict__ dsum,
                                                  unsigned* __restrict__ wlcnt,
                                                  int2* __restrict__ wl, int wlcap) {
    __shared__ __attribute__((aligned(16))) _Float16 zs_hi[64 * 128];   // 16KB
    __shared__ __attribute__((aligned(16))) _Float16 zs_lo[64 * 128];   // 16KB
    __shared__ __attribute__((aligned(16))) char ebuf[4][8192];         // 32KB
    __shared__ __attribute__((aligned(16))) float enls[KK];             // 4KB
    __shared__ int   idx_s[NN][64];
    __shared__ float red_b1[2][64], red_b2[2][64];
    __shared__ int   red_k1[2][64];
    __shared__ float wsum[4];

    const int t   = threadIdx.x;
    const int blk = blockIdx.x;                 // 1024 blocks: 16 per batch
    const int b   = blk >> 4;
    const int hw0 = (blk & 15) << 6;            // 64 consecutive positions
    const int w  = t >> 6, l = t & 63;
    const int pq = w >> 1;                      // p-half (32 rows)
    const int ks = w & 1;                       // k-half (16 of 32 per tile)
    const int tk = l & 15, lg = l >> 4;
    const int koff = ks * 16 + tk;              // lane's code column within a 32-tile

    char* ebase = (char*)&ebuf[0][0];
    const int bo0 = swz(koff, (0 * 32 + lg * 8) * 2);
    const int bo1 = swz(koff, (1 * 32 + lg * 8) * 2);
    const int bo2 = swz(koff, (2 * 32 + lg * 8) * 2);
    const int bo3 = swz(koff, (3 * 32 + lg * 8) * 2);

    const f32x4 zz4   = {0.f, 0.f, 0.f, 0.f};
    const f32x4 m1e30 = {-1e30f, -1e30f, -1e30f, -1e30f};

    float znacc = 0.f, sumb1 = 0.f;

    for (int n = 0; n < NN; ++n) {
        __syncthreads();                        // (A) zs/enls/red reuse guard
        // enorm slice -> LDS (4KB, one gl2lds per thread)
        gl2lds16((const char*)(enormg + n * KK) + t * 16, (char*)enls + t * 16);
        if (n == 0) {                           // prologue: tiles 0,1 -> buf0,buf1
            const char* s0 = ebf + (size_t)0 * 8192 + t * 16;
            gl2lds16(s0, ebase + t * 16);
            gl2lds16(s0 + 4096, ebase + t * 16 + 4096);
            const char* s1 = ebf + (size_t)1 * 8192 + t * 16;
            gl2lds16(s1, ebase + 8192 + t * 16);
            gl2lds16(s1 + 4096, ebase + 8192 + t * 16 + 4096);
        }
        // ---- stage z (fp32 -> fp16 hi/lo, swizzled): row p, thread owns 32 d
        {
            const int p = t & 63, dchunk = t >> 6;
            const float* xp = x + ((size_t)b * CC + n * DD + dchunk * 32) * HW + hw0 + p;
            float fv[32];
            #pragma unroll
            for (int r = 0; r < 32; ++r) fv[r] = xp[(size_t)r * HW];
            #pragma unroll
            for (int j = 0; j < 4; ++j) {
                half8 vh, vl;
                #pragma unroll
                for (int r = 0; r < 8; ++r) {
                    float f = fv[j * 8 + r];
                    _Float16 hh = (_Float16)f;
                    vh[r] = hh;
                    vl[r] = (_Float16)(f - (float)hh);
                    znacc = fmaf(f, f, znacc);
                }
                int o = swz(p, (dchunk * 32 + j * 8) * 2);
                *(half8*)((char*)zs_hi + o) = vh;
                *(half8*)((char*)zs_lo + o) = vl;
            }
        }
        __syncthreads();                        // (B) zs+enls+prologue tiles visible

        // ---- A-fragments in registers for the whole n (16 frags = 64 VGPR)
        half8 a_hi[2][4], a_lo[2][4];
        #pragma unroll
        for (int mf = 0; mf < 2; ++mf)
            #pragma unroll
            for (int ds = 0; ds < 4; ++ds) {
                int o = swz(pq * 32 + mf * 16 + tk, (ds * 32 + lg * 8) * 2);
                a_hi[mf][ds] = *(const half8*)((const char*)zs_hi + o);
                a_lo[mf][ds] = *(const half8*)((const char*)zs_lo + o);
            }

        float b1v[8], b2v[8]; int k1v[8];       // r = mf*4+i -> p = pq*32+mf*16+lg*4+i
        #pragma unroll
        for (int r = 0; r < 8; ++r) { b1v[r] = INFINITY; b2v[r] = INFINITY; k1v[r] = 0; }

        f32x4 accA00, accA01, accA10, accA11;
        f32x4 accB00 = m1e30, accB01 = m1e30, accB10 = m1e30, accB11 = m1e30;
        float e2A = 0.f, e2B = 0.f;

        for (int kt4 = 0; kt4 < 32; kt4 += 4) {
            STEP(0, accA, accB, e2A, e2B)
            STEP(1, accB, accA, e2B, e2A)
            STEP(2, accA, accB, e2A, e2B)
            STEP(3, accB, accA, e2B, e2A)
        }
        // drain: top-2 for kt=31 (parity 1 -> accB)
        TOP2(accB00, accB01, 0, 992 + koff, e2B);
        TOP2(accB10, accB11, 1, 992 + koff, e2B);

        // ---- merge across the 16 lane-columns (tk) of the wave
        #pragma unroll
        for (int off = 1; off < 16; off <<= 1) {
            #pragma unroll
            for (int r = 0; r < 8; ++r) {
                float ob1 = __shfl_xor(b1v[r], off);
                float ob2 = __shfl_xor(b2v[r], off);
                int   ok1 = __shfl_xor(k1v[r], off);
                float nb2 = fminf(b2v[r], ob2);
                if (ob1 < b1v[r] || (ob1 == b1v[r] && ok1 < k1v[r])) {
                    b2v[r] = fminf(nb2, b1v[r]); b1v[r] = ob1; k1v[r] = ok1;
                } else {
                    b2v[r] = fminf(nb2, ob1);
                }
            }
        }
        if (tk == 0) {
            #pragma unroll
            for (int mf = 0; mf < 2; ++mf)
                #pragma unroll
                for (int i = 0; i < 4; ++i) {
                    int p = pq * 32 + mf * 16 + lg * 4 + i, r = mf * 4 + i;
                    red_b1[ks][p] = b1v[r]; red_b2[ks][p] = b2v[r]; red_k1[ks][p] = k1v[r];
                }
        }
        __syncthreads();
        if (t < 64) {                           // merge the 2 k-halves
            int p = t;
            float m1 = red_b1[0][p], m2 = red_b2[0][p]; int mk = red_k1[0][p];
            {
                float ob1 = red_b1[1][p], ob2 = red_b2[1][p]; int ok = red_k1[1][p];
                float nb2 = fminf(m2, ob2);
                if (ob1 < m1 || (ob1 == m1 && ok < mk)) { m2 = fminf(nb2, m1); m1 = ob1; mk = ok; }
                else                                    { m2 = fminf(nb2, ob1); }
            }
            idx_s[n][p] = mk;
            atomicAdd(&hist[n * KK + mk], 1u);
            sumb1 += m1;                        // diff: ||z-q||^2 = znorm + (enorm - 2 z.e)
            if (m2 - m1 < DELTA) {
                unsigned pos = atomicAdd(wlcnt, 1u);
                if ((int)pos < wlcap) wl[pos] = make_int2(b * HW + hw0 + p, n);
            }
        }
    }

    // ---- diff partial reduce
    {
        float tot = znacc + sumb1;
        #pragma unroll
        for (int off = 32; off > 0; off >>= 1) tot += __shfl_down(tot, off);
        if (l == 0) wsum[w] = tot;
        __syncthreads();                        // also guards idx_s for epilogue
        if (t == 0) {
            double sd = 0.0;
            #pragma unroll
            for (int ww = 0; ww < 4; ++ww) sd += (double)wsum[ww];
            atomicAdd(dsum, sd);
        }
    }

    // ---- argmin output (as float): 4n x 64p = one per thread
    {
        int n2 = t >> 6, p = t & 63;
        out[OFF_ARG + (size_t)b * (NN * HW) + (size_t)n2 * HW + hw0 + p] = (float)idx_s[n2][p];
    }

    // ---- z_q gather: contiguous embed_t rows (L2-resident) + coalesced stores
    {
        const int p = t & 63, dchunk = t >> 6;
        #pragma unroll
        for (int n2 = 0; n2 < NN; ++n2) {
            int k = idx_s[n2][p];
            const float4* src = (const float4*)(embt + ((size_t)n2 * KK + k) * DD + dchunk * 32);
            const int c0 = n2 * 128 + dchunk * 32;
            #pragma unroll
            for (int r = 0; r < 8; ++r) {
                float4 q = src[r];
                out[((size_t)b * CC + c0 + r * 4 + 0) * HW + hw0 + p] = q.x;
                out[((size_t)b * CC + c0 + r * 4 + 1) * HW + hw0 + p] = q.y;
                out[((size_t)b * CC + c0 + r * 4 + 2) * HW + hw0 + p] = q.z;
                out[((size_t)b * CC + c0 + r * 4 + 3) * HW + hw0 + p] = q.w;
            }
        }
    }
}

// ---- fp64 exact re-check of near-ties (also fixes hist) --------------------
__global__ __launch_bounds__(256) void vq_refine(const float* __restrict__ x,
                                                 const float* __restrict__ embt,
                                                 float* __restrict__ out,
                                                 unsigned* __restrict__ hist,
                                                 const unsigned* __restrict__ wlcnt,
                                                 const int2* __restrict__ wl, int wlcap) {
    __shared__ double zd[DD];
    __shared__ double sval[256];
    __shared__ int    sidx[256];
    const int t = threadIdx.x;
    unsigned wc = *wlcnt;
    int nitems = (int)(wc < (unsigned)wlcap ? wc : (unsigned)wlcap);

    for (int it = blockIdx.x; it < nitems; it += gridDim.x) {
        int2 item = wl[it];
        int p = item.x, n = item.y;
        int b = p >> 10, hw = p & 1023;
        __syncthreads();
        if (t < DD) zd[t] = (double)x[((size_t)b * CC + n * DD + t) * HW + hw];
        __syncthreads();

        double lb = INFINITY; int lk = 0;
        for (int j = 0; j < 4; ++j) {
            int k = t * 4 + j;
            const float4* er = (const float4*)(embt + ((size_t)n * KK + k) * DD);
            double ss = 0.0, e2 = 0.0;
            #pragma unroll 8
            for (int r = 0; r < 32; ++r) {
                float4 v = er[r];
                double e0 = (double)v.x, e1 = (double)v.y, e2d = (double)v.z, e3 = (double)v.w;
                ss = fma(zd[r*4+0], e0, ss); e2 = fma(e0, e0, e2);
                ss = fma(zd[r*4+1], e1, ss); e2 = fma(e1, e1, e2);
                ss = fma(zd[r*4+2], e2d, ss); e2 = fma(e2d, e2d, e2);
                ss = fma(zd[r*4+3], e3, ss); e2 = fma(e3, e3, e2);
            }
            double dist = e2 - 2.0 * ss;
            if (dist < lb) { lb = dist; lk = k; }
        }
        sval[t] = lb; sidx[t] = lk;
        __syncthreads();
        for (int off = 128; off > 0; off >>= 1) {
            if (t < off) {
                double ov = sval[t + off]; int oi = sidx[t + off];
                if (ov < sval[t] || (ov == sval[t] && oi < sidx[t])) { sval[t] = ov; sidx[t] = oi; }
            }
            __syncthreads();
        }
        if (t == 0) {
            size_t slot = OFF_ARG + (size_t)b * (NN * HW) + (size_t)n * HW + hw;
            int oldk = (int)out[slot];
            int newk = sidx[0];
            if (newk != oldk) {
                out[slot] = (float)newk;
                atomicSub(&hist[n * KK + oldk], 1u);
                atomicAdd(&hist[n * KK + newk], 1u);
            }
        }
    }
}

__global__ __launch_bounds__(256) void vq_final(const unsigned* __restrict__ hist,
                                                const double* __restrict__ dsum,
                                                float* __restrict__ out) {
    __shared__ double red[256];
    __shared__ double hn[NN];
    const int t = threadIdx.x;
    for (int n = 0; n < NN; ++n) {
        double acc = 0.0;
        for (int k = t; k < KK; k += 256) {
            double pr = (double)hist[n * KK + k] / (double)PP;
            acc += pr * log(pr + 1e-10);
        }
        red[t] = acc;
        __syncthreads();
        for (int off = 128; off > 0; off >>= 1) {
            if (t < off) red[t] += red[t + off];
            __syncthreads();
        }
        if (t == 0) hn[n] = red[0];
        __syncthreads();
    }
    if (t == 0) {
        double ppl = 0.0;
        for (int n = 0; n < NN; ++n) ppl += exp(-hn[n]);
        out[OFF_PPL]  = (float)(ppl * 0.25);
        out[OFF_DIFF] = (float)(*dsum / (double)((size_t)BB * CC * HW));
    }
}

extern "C" void kernel_launch(void* const* d_in, const int* in_sizes, int n_in,
                              void* d_out, int out_size, void* d_ws, size_t ws_size,
                              hipStream_t stream) {
    const float* x     = (const float*)d_in[0];
    const float* embed = (const float*)d_in[1];
    float* out = (float*)d_out;
    char*  ws  = (char*)d_ws;

    unsigned* hist   = (unsigned*)(ws + WS_HIST);
    double*   dsum   = (double*)  (ws + WS_DSUM);
    unsigned* wlcnt  = (unsigned*)(ws + WS_WLCNT);
    float*    enorm  = (float*)   (ws + WS_ENORM);
    char*     ebf    = ws + WS_EBF;
    float*    embt   = (float*)   (ws + WS_EMBT);
    int2*     wl     = (int2*)    (ws + WS_WL);

    long long cap = ((long long)ws_size - WS_WL) / (long long)sizeof(int2);
    int wlcap = cap < 0 ? 0 : (cap > 65536 ? 65536 : (int)cap);

    vq_prep  <<<64,   256, 0, stream>>>(embed, ebf, embt, enorm, hist, dsum, wlcnt);
    vq_main  <<<1024, 256, 0, stream>>>(x, ebf, embt, enorm, out, hist, dsum, wlcnt, wl, wlcap);
    vq_refine<<<2048, 256, 0, stream>>>(x, embt, out, hist, wlcnt, wl, wlcap);
    vq_final <<<1,    256, 0, stream>>>(hist, dsum, out);
}